// Round 7
// baseline (387.461 us; speedup 1.0000x reference)
//
#include <hip/hip_runtime.h>
#include <cstdint>
#include <cstddef>

// Problem constants: B=4, S=2048, D=1024, H=4096, M = B*S = 8192.
#define MROWS 8192
#define DDIM  1024
#define HDIM  4096

typedef __bf16 bf16x8 __attribute__((ext_vector_type(8)));
typedef float  f32x4  __attribute__((ext_vector_type(4)));

typedef __attribute__((address_space(1))) void* as1_vp;
typedef __attribute__((address_space(3))) void* as3_vp;

__device__ __forceinline__ unsigned short f2bf(float f) {
  unsigned int u = __builtin_bit_cast(unsigned int, f);
  u += 0x7fffu + ((u >> 16) & 1u);   // RNE
  return (unsigned short)(u >> 16);
}
__device__ __forceinline__ float bf2f(unsigned short h) {
  return __builtin_bit_cast(float, (unsigned int)h << 16);
}

// fast gelu: tanh-form, exp2+rcp based. |err vs exact erf-gelu| < ~1e-3.
__device__ __forceinline__ float fast_gelu(float x) {
  float x3 = x * x * x;
  float z = 0.7978845608028654f * x + 0.03567740814f * x3;
  float e = __builtin_amdgcn_exp2f(z * 2.8853900817779268f); // exp(2z)
  float t = 1.0f - 2.0f * __builtin_amdgcn_rcpf(e + 1.0f);   // tanh(z)
  return 0.5f * x * (1.0f + t);
}

__device__ __forceinline__ void gld_lds16(const unsigned short* g, unsigned short* lds) {
  __builtin_amdgcn_global_load_lds((as1_vp)(uintptr_t)g, (as3_vp)lds, 16, 0, 0);
}

// pre_kernel: blocks [0,8192) convert W1,W2 fp32->bf16; [8192,10240) p1 + xb;
// [10240,10368) zero p2 (required: gemm1 atomicAdds into it, ws is poisoned).
__global__ __launch_bounds__(256) void pre_kernel(
    const float* __restrict__ x, const float* __restrict__ w1,
    const float* __restrict__ w2, unsigned short* __restrict__ xb,
    unsigned short* __restrict__ w1b, unsigned short* __restrict__ w2b,
    float* __restrict__ p1, float* __restrict__ p2) {
  if (blockIdx.x >= 10240) {
    int i = (blockIdx.x - 10240) * 256 + threadIdx.x;  // 0..32767 float4s
    float4 z; z.x = 0.f; z.y = 0.f; z.z = 0.f; z.w = 0.f;
    ((float4*)p2)[i] = z;
    return;
  }
  if (blockIdx.x < 8192) {
    int i = blockIdx.x * 256 + threadIdx.x;     // 0..2097151
    const float* src; unsigned short* dst; int off;
    if (i < 1048576) { src = w1; dst = w1b; off = i; }
    else             { src = w2; dst = w2b; off = i - 1048576; }
    float4 v = ((const float4*)src)[off];
    ushort4 o;
    o.x = f2bf(v.x); o.y = f2bf(v.y); o.z = f2bf(v.z); o.w = f2bf(v.w);
    ((ushort4*)dst)[off] = o;
    return;
  }
  const int bid = blockIdx.x - 8192;
  const int wave = threadIdx.x >> 6, lane = threadIdx.x & 63;
  const int m = bid * 4 + wave;
  const int b = m >> 11;
  const float4* xrow4 = (const float4*)(x + (size_t)m * DDIM);
  const float4* od4   = (const float4*)(x + ((size_t)b * 2048 + 2) * DDIM);
  ushort4* xbrow4 = (ushort4*)(xb + (size_t)m * DDIM);
  float a0 = 0.f, a1 = 0.f, a2 = 0.f, a3 = 0.f;
#pragma unroll
  for (int it = 0; it < 4; ++it) {
    int g = it * 64 + lane;
    float4 v = xrow4[g];
    ushort4 o; o.x = f2bf(v.x); o.y = f2bf(v.y); o.z = f2bf(v.z); o.w = f2bf(v.w);
    xbrow4[g] = o;
    float4 o0 = od4[g];
    float4 o1 = od4[512 + g];
    float4 o2 = od4[1024 + g];
    float4 o3 = od4[1536 + g];
    a0 += v.x * o0.x + v.y * o0.y + v.z * o0.z + v.w * o0.w;
    a1 += v.x * o1.x + v.y * o1.y + v.z * o1.z + v.w * o1.w;
    a2 += v.x * o2.x + v.y * o2.y + v.z * o2.z + v.w * o2.w;
    a3 += v.x * o3.x + v.y * o3.y + v.z * o3.z + v.w * o3.w;
  }
#pragma unroll
  for (int off = 32; off > 0; off >>= 1) {
    a0 += __shfl_down(a0, off);
    a1 += __shfl_down(a1, off);
    a2 += __shfl_down(a2, off);
    a3 += __shfl_down(a3, off);
  }
  if (lane == 0) {
    float4 r; r.x = a0; r.y = a1; r.z = a2; r.w = a3;
    ((float4*)p1)[m] = r;
  }
}

// BK=64 mainloop (gemm1): C(128x128) += A . B^T. LDS 2x16KB. Chunk swizzle
// c=(sl-r)&7 / read slot (c+r)&7 — conflict-free (R3-measured 0).
__device__ __forceinline__ void gemm_bt_tile64(const unsigned short* __restrict__ A,
                                               const unsigned short* __restrict__ B,
                                               const int ld, const int Kloop,
                                               const int m0, const int n0,
                                               unsigned short* As, unsigned short* Bs,
                                               f32x4 acc[4][4]) {
  const int tid  = threadIdx.x;
  const int wave = tid >> 6;
  const int lane = tid & 63;
  const int quad = lane >> 4;
  const int l16  = lane & 15;
  const int wm   = (wave >> 1) * 64;
  const int wn   = (wave & 1) * 64;

  const unsigned short* ga[4]; const unsigned short* gb[4];
#pragma unroll
  for (int s = 0; s < 4; ++s) {
    int idx = wave * 256 + s * 64 + lane;   // linear LDS 16B-slot
    int r = idx >> 3, sl = idx & 7;
    int c = (sl - r) & 7;
    ga[s] = A + (size_t)(m0 + r) * ld + c * 8;
    gb[s] = B + (size_t)(n0 + r) * ld + c * 8;
  }

  for (int k0 = 0; k0 < Kloop; k0 += 64) {
    __syncthreads();
#pragma unroll
    for (int s = 0; s < 4; ++s) gld_lds16(ga[s] + k0, As + (wave * 4 + s) * 512);
#pragma unroll
    for (int s = 0; s < 4; ++s) gld_lds16(gb[s] + k0, Bs + (wave * 4 + s) * 512);
    __syncthreads();
#pragma unroll
    for (int kk = 0; kk < 64; kk += 32) {
      bf16x8 a[4], b[4];
      const int cbase = (kk >> 3) + quad;
#pragma unroll
      for (int i = 0; i < 4; ++i) {
        const int ra = wm + i * 16 + l16;
        const int rb = wn + i * 16 + l16;
        a[i] = *(const bf16x8*)(As + ra * 64 + ((cbase + ra) & 7) * 8);
        b[i] = *(const bf16x8*)(Bs + rb * 64 + ((cbase + rb) & 7) * 8);
      }
#pragma unroll
      for (int i = 0; i < 4; ++i)
#pragma unroll
        for (int j = 0; j < 4; ++j)
          acc[i][j] = __builtin_amdgcn_mfma_f32_16x16x32_bf16(a[i], b[j], acc[i][j], 0, 0, 0);
    }
  }
}

// GEMM1: hact = gelu( x.W1^T + b1 + scale*p1*even ), M=8192 N=4096 K=1024, out bf16.
// XCD swizzle: xcd=id&7 owns m-tiles [xcd*8,xcd*8+8) x all 32 n-tiles (R6, -20% FETCH).
// FUSED p2 partials: this block's fp32 gelu tile contributes
// p2[m, t, seg=n0>>10] += sum_n g[m][n]*x[b,10+2t,n&1023]; reduced over l16 via
// shfl_xor, atomicAdd'ed by lane l16==0 (p2 zeroed in pre_kernel).
__global__ __launch_bounds__(256) void gemm1_kernel(
    const unsigned short* __restrict__ xb, const unsigned short* __restrict__ w1b,
    const float* __restrict__ x, const float* __restrict__ b1,
    const float* __restrict__ p1, const float* __restrict__ scale_p,
    unsigned short* __restrict__ hact, float* __restrict__ p2) {
  __shared__ __align__(16) unsigned short As[128 * 64];
  __shared__ __align__(16) unsigned short Bs[128 * 64];
  const int id = blockIdx.x;
  const int xcd = id & 7, w = id >> 3;
  const int m0 = (xcd * 8 + (w & 7)) * 128;
  const int n0 = (w >> 3) * 128;
  f32x4 acc[4][4];
  const f32x4 z = {0.f, 0.f, 0.f, 0.f};
#pragma unroll
  for (int i = 0; i < 4; ++i)
#pragma unroll
    for (int j = 0; j < 4; ++j) acc[i][j] = z;

  gemm_bt_tile64(xb, w1b, DDIM, DDIM, m0, n0, As, Bs, acc);

  const int tid = threadIdx.x;
  const int wave = tid >> 6, lane = tid & 63, quad = lane >> 4, l16 = lane & 15;
  const int wm = (wave >> 1) * 64, wn = (wave & 1) * 64;
  const float sc = scale_p[0];
  const int bidx = m0 >> 11;
  const int i1 = (n0 + wn) >> 10;            // wave-uniform lora index
  const float* exrow = x + ((size_t)(bidx * 2048 + 1 + 2 * i1)) * DDIM;

  const int seg = n0 >> 10;                  // p2 segment this block feeds
  const int cb  = (n0 & 1023) + wn;          // col base within segment
  float exv[4], b1v[4], odv[4][4]; int nn[4];
#pragma unroll
  for (int j = 0; j < 4; ++j) {
    nn[j]  = n0 + wn + j * 16 + l16;
    exv[j] = exrow[nn[j] & 1023];
    b1v[j] = b1[nn[j]];
    const int c = cb + j * 16 + l16;
#pragma unroll
    for (int t = 0; t < 4; ++t)
      odv[t][j] = x[((size_t)(bidx * 2048 + 10 + 2 * t)) * DDIM + c];
  }
#pragma unroll
  for (int i = 0; i < 4; ++i) {
#pragma unroll
    for (int r = 0; r < 4; ++r) {
      const int m = m0 + wm + i * 16 + quad * 4 + r;
      const float pv = p1[(size_t)m * 4 + i1] * sc;
      float tok[4] = {0.f, 0.f, 0.f, 0.f};
#pragma unroll
      for (int j = 0; j < 4; ++j) {
        float v = acc[i][j][r] + b1v[j] + pv * exv[j];
        float g = fast_gelu(v);
        hact[(size_t)m * HDIM + nn[j]] = f2bf(g);
#pragma unroll
        for (int t = 0; t < 4; ++t) tok[t] += g * odv[t][j];
      }
#pragma unroll
      for (int t = 0; t < 4; ++t) {
        tok[t] += __shfl_xor(tok[t], 1);
        tok[t] += __shfl_xor(tok[t], 2);
        tok[t] += __shfl_xor(tok[t], 4);
        tok[t] += __shfl_xor(tok[t], 8);
      }
      if (l16 == 0) {
        float* pp = p2 + (size_t)m * 16 + seg;
        atomicAdd(pp + 0,  tok[0]);
        atomicAdd(pp + 4,  tok[1]);
        atomicAdd(pp + 8,  tok[2]);
        atomicAdd(pp + 12, tok[3]);
      }
    }
  }
}

// GEMM2: out = hact.W2^T + b2 + scale*<even2, p2[m,i2,:]>, M=8192 N=1024 K=4096.
// BK=128 (64 KB LDS): gemm2 is grid-limited to 2 blocks/CU (512 blocks), so the
// 64 KB costs no occupancy and halves the per-block barrier-drain count (64->32).
// Swizzle generalized mod 16: slot s of row r holds chunk c=(s-r)&15; reader of
// chunk c uses slot (c+r)&15 (same mod-8 bank-residue pattern R3 measured as 0).
// XCD swizzle: n-sweep innermost so 8 blocks sharing an hact m-tile co-reside.
__global__ __launch_bounds__(256) void gemm2_kernel(
    const unsigned short* __restrict__ hact, const unsigned short* __restrict__ w2b,
    const float* __restrict__ x, const float* __restrict__ b2,
    const float* __restrict__ p2, const float* __restrict__ scale_p,
    float* __restrict__ out) {
  __shared__ __align__(16) unsigned short As[128 * 128];
  __shared__ __align__(16) unsigned short Bs[128 * 128];
  const int id = blockIdx.x;
  const int xcd = id & 7, w = id >> 3;
  const int m0 = (xcd * 8 + (w >> 3)) * 128;
  const int n0 = (w & 7) * 128;
  const int tid = threadIdx.x;
  const int wave = tid >> 6, lane = tid & 63, quad = lane >> 4, l16 = lane & 15;
  const int wm = (wave >> 1) * 64, wn = (wave & 1) * 64;
  f32x4 acc[4][4];
  const f32x4 z = {0.f, 0.f, 0.f, 0.f};
#pragma unroll
  for (int i = 0; i < 4; ++i)
#pragma unroll
    for (int j = 0; j < 4; ++j) acc[i][j] = z;

  const unsigned short* ga[8]; const unsigned short* gb[8];
#pragma unroll
  for (int s = 0; s < 8; ++s) {
    int idx = wave * 512 + s * 64 + lane;   // linear 16B-slot, 2048 per matrix
    int r = idx >> 4, sl = idx & 15;
    int c = (sl - r) & 15;
    ga[s] = hact + (size_t)(m0 + r) * HDIM + c * 8;
    gb[s] = w2b  + (size_t)(n0 + r) * HDIM + c * 8;
  }

  for (int k0 = 0; k0 < HDIM; k0 += 128) {
    __syncthreads();
#pragma unroll
    for (int s = 0; s < 8; ++s) gld_lds16(ga[s] + k0, As + (wave * 8 + s) * 512);
#pragma unroll
    for (int s = 0; s < 8; ++s) gld_lds16(gb[s] + k0, Bs + (wave * 8 + s) * 512);
    __syncthreads();
#pragma unroll
    for (int kk = 0; kk < 128; kk += 32) {
      bf16x8 a[4], b[4];
      const int cbase = (kk >> 3) + quad;
#pragma unroll
      for (int i = 0; i < 4; ++i) {
        const int ra = wm + i * 16 + l16;
        const int rb = wn + i * 16 + l16;
        a[i] = *(const bf16x8*)(As + ra * 128 + ((cbase + ra) & 15) * 8);
        b[i] = *(const bf16x8*)(Bs + rb * 128 + ((cbase + rb) & 15) * 8);
      }
#pragma unroll
      for (int i = 0; i < 4; ++i)
#pragma unroll
        for (int j = 0; j < 4; ++j)
          acc[i][j] = __builtin_amdgcn_mfma_f32_16x16x32_bf16(a[i], b[j], acc[i][j], 0, 0, 0);
    }
  }

  const float sc = scale_p[0];
  const int bidx = m0 >> 11;
  const int i2 = (n0 + wn) >> 8;             // wave-uniform
  const float* evrow = x + ((size_t)(bidx * 2048 + 9 + 2 * i2)) * DDIM;

  float4 ev[4]; float b2v[4]; int nn[4];
#pragma unroll
  for (int j = 0; j < 4; ++j) {
    nn[j] = n0 + wn + j * 16 + l16;
    ev[j]  = *(const float4*)(evrow + 4 * (nn[j] & 255));
    b2v[j] = b2[nn[j]];
  }
#pragma unroll
  for (int i = 0; i < 4; ++i) {
#pragma unroll
    for (int r = 0; r < 4; ++r) {
      const int m = m0 + wm + i * 16 + quad * 4 + r;
      const float4 pv = *(const float4*)(p2 + (size_t)m * 16 + i2 * 4);
#pragma unroll
      for (int j = 0; j < 4; ++j) {
        float lora = ev[j].x * pv.x + ev[j].y * pv.y + ev[j].z * pv.z + ev[j].w * pv.w;
        out[(size_t)m * DDIM + nn[j]] = acc[i][j][r] + b2v[j] + sc * lora;
      }
    }
  }
}

extern "C" void kernel_launch(void* const* d_in, const int* in_sizes, int n_in,
                              void* d_out, int out_size, void* d_ws, size_t ws_size,
                              hipStream_t stream) {
  const float* x     = (const float*)d_in[0];
  const float* W1    = (const float*)d_in[1];
  const float* b1    = (const float*)d_in[2];
  const float* W2    = (const float*)d_in[3];
  const float* b2    = (const float*)d_in[4];
  const float* scale = (const float*)d_in[5];
  float* out = (float*)d_out;

  char* ws = (char*)d_ws;
  unsigned short* xb   = (unsigned short*)(ws);                // 16 MiB
  unsigned short* w1b  = (unsigned short*)(ws + 16777216);     //  8 MiB
  unsigned short* w2b  = (unsigned short*)(ws + 25165824);     //  8 MiB
  unsigned short* hact = (unsigned short*)(ws + 33554432);     // 64 MiB
  float*          p1   = (float*)(ws + 100663296);             // 128 KiB
  float*          p2   = (float*)(ws + 100794368);             // 512 KiB

  pre_kernel<<<dim3(10368), dim3(256), 0, stream>>>(x, W1, W2, xb, w1b, w2b, p1, p2);
  gemm1_kernel<<<dim3(2048), dim3(256), 0, stream>>>(xb, w1b, x, b1, p1, scale, hact, p2);
  gemm2_kernel<<<dim3(512), dim3(256), 0, stream>>>(hact, w2b, x, b2, p2, scale, out);
}

// Round 8
// 282.889 us; speedup vs baseline: 1.3697x; 1.3697x over previous
//
#include <hip/hip_runtime.h>
#include <cstdint>
#include <cstddef>

// Problem constants: B=4, S=2048, D=1024, H=4096, M = B*S = 8192.
#define MROWS 8192
#define DDIM  1024
#define HDIM  4096

typedef __bf16 bf16x8 __attribute__((ext_vector_type(8)));
typedef float  f32x4  __attribute__((ext_vector_type(4)));

typedef __attribute__((address_space(1))) void* as1_vp;
typedef __attribute__((address_space(3))) void* as3_vp;

__device__ __forceinline__ unsigned short f2bf(float f) {
  unsigned int u = __builtin_bit_cast(unsigned int, f);
  u += 0x7fffu + ((u >> 16) & 1u);   // RNE
  return (unsigned short)(u >> 16);
}
__device__ __forceinline__ float bf2f(unsigned short h) {
  return __builtin_bit_cast(float, (unsigned int)h << 16);
}

// fast gelu: tanh-form, exp2+rcp based. |err vs exact erf-gelu| < ~1e-3.
__device__ __forceinline__ float fast_gelu(float x) {
  float x3 = x * x * x;
  float z = 0.7978845608028654f * x + 0.03567740814f * x3;
  float e = __builtin_amdgcn_exp2f(z * 2.8853900817779268f); // exp(2z)
  float t = 1.0f - 2.0f * __builtin_amdgcn_rcpf(e + 1.0f);   // tanh(z)
  return 0.5f * x * (1.0f + t);
}

__device__ __forceinline__ void gld_lds16(const unsigned short* g, unsigned short* lds) {
  __builtin_amdgcn_global_load_lds((as1_vp)(uintptr_t)g, (as3_vp)lds, 16, 0, 0);
}

// pre_kernel: blocks [0,8192) convert W1,W2 fp32->bf16 (float4 granule);
// blocks [8192,10240) do p1 (wave per row) and emit xb.
// NOTE (R7 lesson): p1/p2 must be produced by BLOCK-LOCAL reductions only —
// cross-block atomic fusion ping-pongs cache lines across XCDs (96->216 us).
__global__ __launch_bounds__(256) void pre_kernel(
    const float* __restrict__ x, const float* __restrict__ w1,
    const float* __restrict__ w2, unsigned short* __restrict__ xb,
    unsigned short* __restrict__ w1b, unsigned short* __restrict__ w2b,
    float* __restrict__ p1) {
  if (blockIdx.x < 8192) {
    int i = blockIdx.x * 256 + threadIdx.x;     // 0..2097151
    const float* src; unsigned short* dst; int off;
    if (i < 1048576) { src = w1; dst = w1b; off = i; }
    else             { src = w2; dst = w2b; off = i - 1048576; }
    float4 v = ((const float4*)src)[off];
    ushort4 o;
    o.x = f2bf(v.x); o.y = f2bf(v.y); o.z = f2bf(v.z); o.w = f2bf(v.w);
    ((ushort4*)dst)[off] = o;
    return;
  }
  const int bid = blockIdx.x - 8192;
  const int wave = threadIdx.x >> 6, lane = threadIdx.x & 63;
  const int m = bid * 4 + wave;
  const int b = m >> 11;
  const float4* xrow4 = (const float4*)(x + (size_t)m * DDIM);
  const float4* od4   = (const float4*)(x + ((size_t)b * 2048 + 2) * DDIM);
  ushort4* xbrow4 = (ushort4*)(xb + (size_t)m * DDIM);
  float a0 = 0.f, a1 = 0.f, a2 = 0.f, a3 = 0.f;
#pragma unroll
  for (int it = 0; it < 4; ++it) {
    int g = it * 64 + lane;
    float4 v = xrow4[g];
    ushort4 o; o.x = f2bf(v.x); o.y = f2bf(v.y); o.z = f2bf(v.z); o.w = f2bf(v.w);
    xbrow4[g] = o;
    float4 o0 = od4[g];
    float4 o1 = od4[512 + g];
    float4 o2 = od4[1024 + g];
    float4 o3 = od4[1536 + g];
    a0 += v.x * o0.x + v.y * o0.y + v.z * o0.z + v.w * o0.w;
    a1 += v.x * o1.x + v.y * o1.y + v.z * o1.z + v.w * o1.w;
    a2 += v.x * o2.x + v.y * o2.y + v.z * o2.z + v.w * o2.w;
    a3 += v.x * o3.x + v.y * o3.y + v.z * o3.z + v.w * o3.w;
  }
#pragma unroll
  for (int off = 32; off > 0; off >>= 1) {
    a0 += __shfl_down(a0, off);
    a1 += __shfl_down(a1, off);
    a2 += __shfl_down(a2, off);
    a3 += __shfl_down(a3, off);
  }
  if (lane == 0) {
    float4 r; r.x = a0; r.y = a1; r.z = a2; r.w = a3;
    ((float4*)p1)[m] = r;
  }
}

// p2[m, i*4+r] = dot(hact[m, r*1024:...], x[b, 10+2i, :]). Wave per row; grid 2048.
__global__ __launch_bounds__(256) void p2_kernel(const unsigned short* __restrict__ hact,
                                                 const float* __restrict__ x,
                                                 float* __restrict__ p2) {
  const int wave = threadIdx.x >> 6, lane = threadIdx.x & 63;
  const int m = blockIdx.x * 4 + wave;
  const int b = m >> 11;
  const ushort4* hrow4 = (const ushort4*)(hact + (size_t)m * HDIM);
  const float4* od4    = (const float4*)(x + ((size_t)b * 2048 + 10) * DDIM);
  float acc[4][4] = {{0.f}};
#pragma unroll
  for (int it = 0; it < 4; ++it) {
    int g = it * 64 + lane;
    float h[4][4];
#pragma unroll
    for (int r = 0; r < 4; ++r) {
      ushort4 hv = hrow4[r * 256 + g];
      h[r][0] = bf2f(hv.x); h[r][1] = bf2f(hv.y); h[r][2] = bf2f(hv.z); h[r][3] = bf2f(hv.w);
    }
#pragma unroll
    for (int i = 0; i < 4; ++i) {
      float4 ov = od4[i * 512 + g];
#pragma unroll
      for (int r = 0; r < 4; ++r)
        acc[i][r] += ov.x * h[r][0] + ov.y * h[r][1] + ov.z * h[r][2] + ov.w * h[r][3];
    }
  }
#pragma unroll
  for (int i = 0; i < 4; ++i)
#pragma unroll
    for (int r = 0; r < 4; ++r)
#pragma unroll
      for (int off = 32; off > 0; off >>= 1)
        acc[i][r] += __shfl_down(acc[i][r], off);
  if (lane == 0) {
#pragma unroll
    for (int i = 0; i < 4; ++i) {
      float4 v; v.x = acc[i][0]; v.y = acc[i][1]; v.z = acc[i][2]; v.w = acc[i][3];
      ((float4*)(p2 + (size_t)m * 16))[i] = v;
    }
  }
}

// BK=64 mainloop (gemm1): C(128x128) += A . B^T. LDS 2x16KB. Chunk swizzle
// c=(sl-r)&7 / read slot (c+r)&7 — conflict-free (R3-measured 0).
__device__ __forceinline__ void gemm_bt_tile64(const unsigned short* __restrict__ A,
                                               const unsigned short* __restrict__ B,
                                               const int ld, const int Kloop,
                                               const int m0, const int n0,
                                               unsigned short* As, unsigned short* Bs,
                                               f32x4 acc[4][4]) {
  const int tid  = threadIdx.x;
  const int wave = tid >> 6;
  const int lane = tid & 63;
  const int quad = lane >> 4;
  const int l16  = lane & 15;
  const int wm   = (wave >> 1) * 64;
  const int wn   = (wave & 1) * 64;

  const unsigned short* ga[4]; const unsigned short* gb[4];
#pragma unroll
  for (int s = 0; s < 4; ++s) {
    int idx = wave * 256 + s * 64 + lane;   // linear LDS 16B-slot
    int r = idx >> 3, sl = idx & 7;
    int c = (sl - r) & 7;
    ga[s] = A + (size_t)(m0 + r) * ld + c * 8;
    gb[s] = B + (size_t)(n0 + r) * ld + c * 8;
  }

  for (int k0 = 0; k0 < Kloop; k0 += 64) {
    __syncthreads();
#pragma unroll
    for (int s = 0; s < 4; ++s) gld_lds16(ga[s] + k0, As + (wave * 4 + s) * 512);
#pragma unroll
    for (int s = 0; s < 4; ++s) gld_lds16(gb[s] + k0, Bs + (wave * 4 + s) * 512);
    __syncthreads();
#pragma unroll
    for (int kk = 0; kk < 64; kk += 32) {
      bf16x8 a[4], b[4];
      const int cbase = (kk >> 3) + quad;
#pragma unroll
      for (int i = 0; i < 4; ++i) {
        const int ra = wm + i * 16 + l16;
        const int rb = wn + i * 16 + l16;
        a[i] = *(const bf16x8*)(As + ra * 64 + ((cbase + ra) & 7) * 8);
        b[i] = *(const bf16x8*)(Bs + rb * 64 + ((cbase + rb) & 7) * 8);
      }
#pragma unroll
      for (int i = 0; i < 4; ++i)
#pragma unroll
        for (int j = 0; j < 4; ++j)
          acc[i][j] = __builtin_amdgcn_mfma_f32_16x16x32_bf16(a[i], b[j], acc[i][j], 0, 0, 0);
    }
  }
}

// GEMM1: hact = gelu( x.W1^T + b1 + scale*p1*even ), M=8192 N=4096 K=1024, out bf16.
// XCD swizzle: xcd=id&7 owns m-tiles [xcd*8,xcd*8+8) x all 32 n-tiles (R6, -20% FETCH).
__global__ __launch_bounds__(256) void gemm1_kernel(
    const unsigned short* __restrict__ xb, const unsigned short* __restrict__ w1b,
    const float* __restrict__ x, const float* __restrict__ b1,
    const float* __restrict__ p1, const float* __restrict__ scale_p,
    unsigned short* __restrict__ hact) {
  __shared__ __align__(16) unsigned short As[128 * 64];
  __shared__ __align__(16) unsigned short Bs[128 * 64];
  const int id = blockIdx.x;
  const int xcd = id & 7, w = id >> 3;
  const int m0 = (xcd * 8 + (w & 7)) * 128;
  const int n0 = (w >> 3) * 128;
  f32x4 acc[4][4];
  const f32x4 z = {0.f, 0.f, 0.f, 0.f};
#pragma unroll
  for (int i = 0; i < 4; ++i)
#pragma unroll
    for (int j = 0; j < 4; ++j) acc[i][j] = z;

  gemm_bt_tile64(xb, w1b, DDIM, DDIM, m0, n0, As, Bs, acc);

  const int tid = threadIdx.x;
  const int wave = tid >> 6, lane = tid & 63, quad = lane >> 4, l16 = lane & 15;
  const int wm = (wave >> 1) * 64, wn = (wave & 1) * 64;
  const float sc = scale_p[0];
  const int bidx = m0 >> 11;
  const int i1 = (n0 + wn) >> 10;            // wave-uniform lora index
  const float* exrow = x + ((size_t)(bidx * 2048 + 1 + 2 * i1)) * DDIM;

  float exv[4], b1v[4]; int nn[4];
#pragma unroll
  for (int j = 0; j < 4; ++j) {
    nn[j]  = n0 + wn + j * 16 + l16;
    exv[j] = exrow[nn[j] & 1023];
    b1v[j] = b1[nn[j]];
  }
#pragma unroll
  for (int i = 0; i < 4; ++i) {
#pragma unroll
    for (int r = 0; r < 4; ++r) {
      const int m = m0 + wm + i * 16 + quad * 4 + r;
      const float pv = p1[(size_t)m * 4 + i1] * sc;
#pragma unroll
      for (int j = 0; j < 4; ++j) {
        float v = acc[i][j][r] + b1v[j] + pv * exv[j];
        hact[(size_t)m * HDIM + nn[j]] = f2bf(fast_gelu(v));
      }
    }
  }
}

// GEMM2: out = hact.W2^T + b2 + scale*<even2, p2[m,i2,:]>, M=8192 N=1024 K=4096.
// BK=128 (64 KB LDS): gemm2 is grid-limited to 2 blocks/CU (512 blocks), so the
// 64 KB costs no occupancy and halves the per-block barrier-drain count (64->32).
// Swizzle mod 16: slot s of row r holds chunk c=(s-r)&15; reader uses (c+r)&15.
// XCD swizzle: n-sweep innermost so 8 blocks sharing an hact m-tile co-reside.
__global__ __launch_bounds__(256) void gemm2_kernel(
    const unsigned short* __restrict__ hact, const unsigned short* __restrict__ w2b,
    const float* __restrict__ x, const float* __restrict__ b2,
    const float* __restrict__ p2, const float* __restrict__ scale_p,
    float* __restrict__ out) {
  __shared__ __align__(16) unsigned short As[128 * 128];
  __shared__ __align__(16) unsigned short Bs[128 * 128];
  const int id = blockIdx.x;
  const int xcd = id & 7, w = id >> 3;
  const int m0 = (xcd * 8 + (w >> 3)) * 128;
  const int n0 = (w & 7) * 128;
  const int tid = threadIdx.x;
  const int wave = tid >> 6, lane = tid & 63, quad = lane >> 4, l16 = lane & 15;
  const int wm = (wave >> 1) * 64, wn = (wave & 1) * 64;
  f32x4 acc[4][4];
  const f32x4 z = {0.f, 0.f, 0.f, 0.f};
#pragma unroll
  for (int i = 0; i < 4; ++i)
#pragma unroll
    for (int j = 0; j < 4; ++j) acc[i][j] = z;

  const unsigned short* ga[8]; const unsigned short* gb[8];
#pragma unroll
  for (int s = 0; s < 8; ++s) {
    int idx = wave * 512 + s * 64 + lane;   // linear 16B-slot, 2048 per matrix
    int r = idx >> 4, sl = idx & 15;
    int c = (sl - r) & 15;
    ga[s] = hact + (size_t)(m0 + r) * HDIM + c * 8;
    gb[s] = w2b  + (size_t)(n0 + r) * HDIM + c * 8;
  }

  for (int k0 = 0; k0 < HDIM; k0 += 128) {
    __syncthreads();
#pragma unroll
    for (int s = 0; s < 8; ++s) gld_lds16(ga[s] + k0, As + (wave * 8 + s) * 512);
#pragma unroll
    for (int s = 0; s < 8; ++s) gld_lds16(gb[s] + k0, Bs + (wave * 8 + s) * 512);
    __syncthreads();
#pragma unroll
    for (int kk = 0; kk < 128; kk += 32) {
      bf16x8 a[4], b[4];
      const int cbase = (kk >> 3) + quad;
#pragma unroll
      for (int i = 0; i < 4; ++i) {
        const int ra = wm + i * 16 + l16;
        const int rb = wn + i * 16 + l16;
        a[i] = *(const bf16x8*)(As + ra * 128 + ((cbase + ra) & 15) * 8);
        b[i] = *(const bf16x8*)(Bs + rb * 128 + ((cbase + rb) & 15) * 8);
      }
#pragma unroll
      for (int i = 0; i < 4; ++i)
#pragma unroll
        for (int j = 0; j < 4; ++j)
          acc[i][j] = __builtin_amdgcn_mfma_f32_16x16x32_bf16(a[i], b[j], acc[i][j], 0, 0, 0);
    }
  }

  const float sc = scale_p[0];
  const int bidx = m0 >> 11;
  const int i2 = (n0 + wn) >> 8;             // wave-uniform
  const float* evrow = x + ((size_t)(bidx * 2048 + 9 + 2 * i2)) * DDIM;

  float4 ev[4]; float b2v[4]; int nn[4];
#pragma unroll
  for (int j = 0; j < 4; ++j) {
    nn[j] = n0 + wn + j * 16 + l16;
    ev[j]  = *(const float4*)(evrow + 4 * (nn[j] & 255));
    b2v[j] = b2[nn[j]];
  }
#pragma unroll
  for (int i = 0; i < 4; ++i) {
#pragma unroll
    for (int r = 0; r < 4; ++r) {
      const int m = m0 + wm + i * 16 + quad * 4 + r;
      const float4 pv = *(const float4*)(p2 + (size_t)m * 16 + i2 * 4);
#pragma unroll
      for (int j = 0; j < 4; ++j) {
        float lora = ev[j].x * pv.x + ev[j].y * pv.y + ev[j].z * pv.z + ev[j].w * pv.w;
        out[(size_t)m * DDIM + nn[j]] = acc[i][j][r] + b2v[j] + sc * lora;
      }
    }
  }
}

extern "C" void kernel_launch(void* const* d_in, const int* in_sizes, int n_in,
                              void* d_out, int out_size, void* d_ws, size_t ws_size,
                              hipStream_t stream) {
  const float* x     = (const float*)d_in[0];
  const float* W1    = (const float*)d_in[1];
  const float* b1    = (const float*)d_in[2];
  const float* W2    = (const float*)d_in[3];
  const float* b2    = (const float*)d_in[4];
  const float* scale = (const float*)d_in[5];
  float* out = (float*)d_out;

  char* ws = (char*)d_ws;
  unsigned short* xb   = (unsigned short*)(ws);                // 16 MiB
  unsigned short* w1b  = (unsigned short*)(ws + 16777216);     //  8 MiB
  unsigned short* w2b  = (unsigned short*)(ws + 25165824);     //  8 MiB
  unsigned short* hact = (unsigned short*)(ws + 33554432);     // 64 MiB
  float*          p1   = (float*)(ws + 100663296);             // 128 KiB
  float*          p2   = (float*)(ws + 100794368);             // 512 KiB

  pre_kernel<<<dim3(10240), dim3(256), 0, stream>>>(x, W1, W2, xb, w1b, w2b, p1);
  gemm1_kernel<<<dim3(2048), dim3(256), 0, stream>>>(xb, w1b, x, b1, p1, scale, hact);
  p2_kernel<<<dim3(2048), dim3(256), 0, stream>>>(hact, x, p2);
  gemm2_kernel<<<dim3(512), dim3(256), 0, stream>>>(hact, w2b, x, b2, p2, scale, out);
}

// Round 9
// 274.353 us; speedup vs baseline: 1.4123x; 1.0311x over previous
//
#include <hip/hip_runtime.h>
#include <cstdint>
#include <cstddef>

// Problem constants: B=4, S=2048, D=1024, H=4096, M = B*S = 8192.
#define MROWS 8192
#define DDIM  1024
#define HDIM  4096

typedef __bf16 bf16x8 __attribute__((ext_vector_type(8)));
typedef float  f32x4  __attribute__((ext_vector_type(4)));

typedef __attribute__((address_space(1))) void* as1_vp;
typedef __attribute__((address_space(3))) void* as3_vp;

__device__ __forceinline__ unsigned short f2bf(float f) {
  unsigned int u = __builtin_bit_cast(unsigned int, f);
  u += 0x7fffu + ((u >> 16) & 1u);   // RNE
  return (unsigned short)(u >> 16);
}
__device__ __forceinline__ float bf2f(unsigned short h) {
  return __builtin_bit_cast(float, (unsigned int)h << 16);
}

// fast gelu: tanh-form, exp2+rcp based. |err vs exact erf-gelu| < ~1e-3.
__device__ __forceinline__ float fast_gelu(float x) {
  float x3 = x * x * x;
  float z = 0.7978845608028654f * x + 0.03567740814f * x3;
  float e = __builtin_amdgcn_exp2f(z * 2.8853900817779268f); // exp(2z)
  float t = 1.0f - 2.0f * __builtin_amdgcn_rcpf(e + 1.0f);   // tanh(z)
  return 0.5f * x * (1.0f + t);
}

__device__ __forceinline__ void gld_lds16(const unsigned short* g, unsigned short* lds) {
  __builtin_amdgcn_global_load_lds((as1_vp)(uintptr_t)g, (as3_vp)lds, 16, 0, 0);
}

// pre_kernel: blocks [0,8192) convert W1,W2 fp32->bf16 (float4 granule);
// blocks [8192,10240) do p1 (wave per row) and emit xb.
// NOTE (R7 lesson): p1/p2 must be produced by BLOCK-LOCAL reductions only —
// cross-block atomic fusion ping-pongs cache lines across XCDs (96->216 us).
__global__ __launch_bounds__(256) void pre_kernel(
    const float* __restrict__ x, const float* __restrict__ w1,
    const float* __restrict__ w2, unsigned short* __restrict__ xb,
    unsigned short* __restrict__ w1b, unsigned short* __restrict__ w2b,
    float* __restrict__ p1) {
  if (blockIdx.x < 8192) {
    int i = blockIdx.x * 256 + threadIdx.x;     // 0..2097151
    const float* src; unsigned short* dst; int off;
    if (i < 1048576) { src = w1; dst = w1b; off = i; }
    else             { src = w2; dst = w2b; off = i - 1048576; }
    float4 v = ((const float4*)src)[off];
    ushort4 o;
    o.x = f2bf(v.x); o.y = f2bf(v.y); o.z = f2bf(v.z); o.w = f2bf(v.w);
    ((ushort4*)dst)[off] = o;
    return;
  }
  const int bid = blockIdx.x - 8192;
  const int wave = threadIdx.x >> 6, lane = threadIdx.x & 63;
  const int m = bid * 4 + wave;
  const int b = m >> 11;
  const float4* xrow4 = (const float4*)(x + (size_t)m * DDIM);
  const float4* od4   = (const float4*)(x + ((size_t)b * 2048 + 2) * DDIM);
  ushort4* xbrow4 = (ushort4*)(xb + (size_t)m * DDIM);
  float a0 = 0.f, a1 = 0.f, a2 = 0.f, a3 = 0.f;
#pragma unroll
  for (int it = 0; it < 4; ++it) {
    int g = it * 64 + lane;
    float4 v = xrow4[g];
    ushort4 o; o.x = f2bf(v.x); o.y = f2bf(v.y); o.z = f2bf(v.z); o.w = f2bf(v.w);
    xbrow4[g] = o;
    float4 o0 = od4[g];
    float4 o1 = od4[512 + g];
    float4 o2 = od4[1024 + g];
    float4 o3 = od4[1536 + g];
    a0 += v.x * o0.x + v.y * o0.y + v.z * o0.z + v.w * o0.w;
    a1 += v.x * o1.x + v.y * o1.y + v.z * o1.z + v.w * o1.w;
    a2 += v.x * o2.x + v.y * o2.y + v.z * o2.z + v.w * o2.w;
    a3 += v.x * o3.x + v.y * o3.y + v.z * o3.z + v.w * o3.w;
  }
#pragma unroll
  for (int off = 32; off > 0; off >>= 1) {
    a0 += __shfl_down(a0, off);
    a1 += __shfl_down(a1, off);
    a2 += __shfl_down(a2, off);
    a3 += __shfl_down(a3, off);
  }
  if (lane == 0) {
    float4 r; r.x = a0; r.y = a1; r.z = a2; r.w = a3;
    ((float4*)p1)[m] = r;
  }
}

// BK=64 mainloop (gemm1): C(128x128) += A . B^T. LDS 2x16KB. Chunk swizzle
// c=(sl-r)&7 / read slot (c+r)&7 — conflict-free (R3-measured 0).
__device__ __forceinline__ void gemm_bt_tile64(const unsigned short* __restrict__ A,
                                               const unsigned short* __restrict__ B,
                                               const int ld, const int Kloop,
                                               const int m0, const int n0,
                                               unsigned short* As, unsigned short* Bs,
                                               f32x4 acc[4][4]) {
  const int tid  = threadIdx.x;
  const int wave = tid >> 6;
  const int lane = tid & 63;
  const int quad = lane >> 4;
  const int l16  = lane & 15;
  const int wm   = (wave >> 1) * 64;
  const int wn   = (wave & 1) * 64;

  const unsigned short* ga[4]; const unsigned short* gb[4];
#pragma unroll
  for (int s = 0; s < 4; ++s) {
    int idx = wave * 256 + s * 64 + lane;   // linear LDS 16B-slot
    int r = idx >> 3, sl = idx & 7;
    int c = (sl - r) & 7;
    ga[s] = A + (size_t)(m0 + r) * ld + c * 8;
    gb[s] = B + (size_t)(n0 + r) * ld + c * 8;
  }

  for (int k0 = 0; k0 < Kloop; k0 += 64) {
    __syncthreads();
#pragma unroll
    for (int s = 0; s < 4; ++s) gld_lds16(ga[s] + k0, As + (wave * 4 + s) * 512);
#pragma unroll
    for (int s = 0; s < 4; ++s) gld_lds16(gb[s] + k0, Bs + (wave * 4 + s) * 512);
    __syncthreads();
#pragma unroll
    for (int kk = 0; kk < 64; kk += 32) {
      bf16x8 a[4], b[4];
      const int cbase = (kk >> 3) + quad;
#pragma unroll
      for (int i = 0; i < 4; ++i) {
        const int ra = wm + i * 16 + l16;
        const int rb = wn + i * 16 + l16;
        a[i] = *(const bf16x8*)(As + ra * 64 + ((cbase + ra) & 7) * 8);
        b[i] = *(const bf16x8*)(Bs + rb * 64 + ((cbase + rb) & 7) * 8);
      }
#pragma unroll
      for (int i = 0; i < 4; ++i)
#pragma unroll
        for (int j = 0; j < 4; ++j)
          acc[i][j] = __builtin_amdgcn_mfma_f32_16x16x32_bf16(a[i], b[j], acc[i][j], 0, 0, 0);
    }
  }
}

// GEMM1: hact = gelu( x.W1^T + b1 + scale*p1*even ), M=8192 N=4096 K=1024, out bf16.
// XCD swizzle: xcd=id&7 owns m-tiles [xcd*8,xcd*8+8) x all 32 n-tiles (R6, -20% FETCH).
__global__ __launch_bounds__(256) void gemm1_kernel(
    const unsigned short* __restrict__ xb, const unsigned short* __restrict__ w1b,
    const float* __restrict__ x, const float* __restrict__ b1,
    const float* __restrict__ p1, const float* __restrict__ scale_p,
    unsigned short* __restrict__ hact) {
  __shared__ __align__(16) unsigned short As[128 * 64];
  __shared__ __align__(16) unsigned short Bs[128 * 64];
  const int id = blockIdx.x;
  const int xcd = id & 7, w = id >> 3;
  const int m0 = (xcd * 8 + (w & 7)) * 128;
  const int n0 = (w >> 3) * 128;
  f32x4 acc[4][4];
  const f32x4 z = {0.f, 0.f, 0.f, 0.f};
#pragma unroll
  for (int i = 0; i < 4; ++i)
#pragma unroll
    for (int j = 0; j < 4; ++j) acc[i][j] = z;

  gemm_bt_tile64(xb, w1b, DDIM, DDIM, m0, n0, As, Bs, acc);

  const int tid = threadIdx.x;
  const int wave = tid >> 6, lane = tid & 63, quad = lane >> 4, l16 = lane & 15;
  const int wm = (wave >> 1) * 64, wn = (wave & 1) * 64;
  const float sc = scale_p[0];
  const int bidx = m0 >> 11;
  const int i1 = (n0 + wn) >> 10;            // wave-uniform lora index
  const float* exrow = x + ((size_t)(bidx * 2048 + 1 + 2 * i1)) * DDIM;

  float exv[4], b1v[4]; int nn[4];
#pragma unroll
  for (int j = 0; j < 4; ++j) {
    nn[j]  = n0 + wn + j * 16 + l16;
    exv[j] = exrow[nn[j] & 1023];
    b1v[j] = b1[nn[j]];
  }
#pragma unroll
  for (int i = 0; i < 4; ++i) {
#pragma unroll
    for (int r = 0; r < 4; ++r) {
      const int m = m0 + wm + i * 16 + quad * 4 + r;
      const float pv = p1[(size_t)m * 4 + i1] * sc;
#pragma unroll
      for (int j = 0; j < 4; ++j) {
        float v = acc[i][j][r] + b1v[j] + pv * exv[j];
        hact[(size_t)m * HDIM + nn[j]] = f2bf(fast_gelu(v));
      }
    }
  }
}

// GEMM2 with MFMA-FUSED p2: out = hact.W2^T + b2 + scale*<even2, p2[m,i2,:]>.
// M=8192 N=1024 K=4096, BK=128 (R8). Each block needs only p2[m, i2*4+r] for its
// block-uniform i2 = n0>>8 and its own 128 rows — BLOCK-LOCAL (R7 lesson).
// The dot rides the matrix pipe: b_od fragment = od row (bf16, LDS) in column 0
// only; pacc = mfma(a[i], b_od, pacc) on waves wn==0 (rows covered exactly once).
// Segment r = k0>>10; pacc column 0 flushed to LDS every 8 k0-iters.
// od in bf16 adds ~3e-4 absmax (p2 contribution ~0.08 * 0.4% rel) — negligible.
__global__ __launch_bounds__(256) void gemm2_kernel(
    const unsigned short* __restrict__ hact, const unsigned short* __restrict__ w2b,
    const float* __restrict__ x, const float* __restrict__ b2,
    const float* __restrict__ scale_p, float* __restrict__ out) {
  __shared__ __align__(16) unsigned short As[128 * 128];
  __shared__ __align__(16) unsigned short Bs[128 * 128];
  __shared__ __align__(16) unsigned short od_lds[1024];   // 2 KB
  __shared__ __align__(16) float p2s[128 * 4];            // 2 KB
  const int id = blockIdx.x;
  const int xcd = id & 7, w = id >> 3;
  const int m0 = (xcd * 8 + (w >> 3)) * 128;
  const int n0 = (w & 7) * 128;
  const int tid = threadIdx.x;
  const int wave = tid >> 6, lane = tid & 63, quad = lane >> 4, l16 = lane & 15;
  const int wm = (wave >> 1) * 64, wn = (wave & 1) * 64;
  const int bidx = m0 >> 11;
  const int i2 = n0 >> 8;                    // block-uniform lora index

  // preload od row (odd token 4+i2) as bf16: 1024 floats, 4 per thread
  {
    const float4* src = (const float4*)(x + ((size_t)(bidx * 2048 + 10 + 2 * i2)) * DDIM);
    float4 v = src[tid];
    ushort4 o; o.x = f2bf(v.x); o.y = f2bf(v.y); o.z = f2bf(v.z); o.w = f2bf(v.w);
    ((ushort4*)od_lds)[tid] = o;
  }

  f32x4 acc[4][4];
  const f32x4 z = {0.f, 0.f, 0.f, 0.f};
#pragma unroll
  for (int i = 0; i < 4; ++i)
#pragma unroll
    for (int j = 0; j < 4; ++j) acc[i][j] = z;
  f32x4 pacc[4] = {z, z, z, z};
  const bf16x8 zer8 = __builtin_bit_cast(bf16x8, z);

  const unsigned short* ga[8]; const unsigned short* gb[8];
#pragma unroll
  for (int s = 0; s < 8; ++s) {
    int idx = wave * 512 + s * 64 + lane;   // linear 16B-slot, 2048 per matrix
    int r = idx >> 4, sl = idx & 15;
    int c = (sl - r) & 15;
    ga[s] = hact + (size_t)(m0 + r) * HDIM + c * 8;
    gb[s] = w2b  + (size_t)(n0 + r) * HDIM + c * 8;
  }

  for (int k0 = 0; k0 < HDIM; k0 += 128) {
    __syncthreads();   // also orders the od_lds preload before first use
#pragma unroll
    for (int s = 0; s < 8; ++s) gld_lds16(ga[s] + k0, As + (wave * 8 + s) * 512);
#pragma unroll
    for (int s = 0; s < 8; ++s) gld_lds16(gb[s] + k0, Bs + (wave * 8 + s) * 512);
    __syncthreads();
    const int odbase = k0 & 1023;
#pragma unroll
    for (int kk = 0; kk < 128; kk += 32) {
      bf16x8 a[4], b[4];
      const int cbase = (kk >> 3) + quad;
#pragma unroll
      for (int i = 0; i < 4; ++i) {
        const int ra = wm + i * 16 + l16;
        const int rb = wn + i * 16 + l16;
        a[i] = *(const bf16x8*)(As + ra * 128 + ((cbase + ra) & 15) * 8);
        b[i] = *(const bf16x8*)(Bs + rb * 128 + ((cbase + rb) & 15) * 8);
      }
      if (wn == 0) {   // waves 0,2: rows 0-63 / 64-127 — each row exactly once
        bf16x8 odv = *(const bf16x8*)(od_lds + odbase + kk + quad * 8);  // broadcast read
        bf16x8 bod = (l16 == 0) ? odv : zer8;   // od in column 0 only
#pragma unroll
        for (int i = 0; i < 4; ++i)
          pacc[i] = __builtin_amdgcn_mfma_f32_16x16x32_bf16(a[i], bod, pacc[i], 0, 0, 0);
      }
#pragma unroll
      for (int i = 0; i < 4; ++i)
#pragma unroll
        for (int j = 0; j < 4; ++j)
          acc[i][j] = __builtin_amdgcn_mfma_f32_16x16x32_bf16(a[i], b[j], acc[i][j], 0, 0, 0);
    }
    if (((k0 + 128) & 1023) == 0) {          // segment boundary: flush column 0
      const int seg = k0 >> 10;
      if (wn == 0) {
        if (l16 == 0) {
#pragma unroll
          for (int i = 0; i < 4; ++i)
#pragma unroll
            for (int e = 0; e < 4; ++e)
              p2s[(wm + i * 16 + quad * 4 + e) * 4 + seg] = pacc[i][e];
        }
#pragma unroll
        for (int i = 0; i < 4; ++i) pacc[i] = z;
      }
    }
  }
  __syncthreads();                           // p2s visible to all waves

  const float sc = scale_p[0];
  const float* evrow = x + ((size_t)(bidx * 2048 + 9 + 2 * i2)) * DDIM;

  float4 ev[4]; float b2v[4]; int nn[4];
#pragma unroll
  for (int j = 0; j < 4; ++j) {
    nn[j] = n0 + wn + j * 16 + l16;
    ev[j]  = *(const float4*)(evrow + 4 * (nn[j] & 255));
    b2v[j] = b2[nn[j]];
  }
#pragma unroll
  for (int i = 0; i < 4; ++i) {
#pragma unroll
    for (int r = 0; r < 4; ++r) {
      const int mloc = wm + i * 16 + quad * 4 + r;
      const int m = m0 + mloc;
      const float4 pv = *(const float4*)(p2s + mloc * 4);  // broadcast across l16
#pragma unroll
      for (int j = 0; j < 4; ++j) {
        float lora = ev[j].x * pv.x + ev[j].y * pv.y + ev[j].z * pv.z + ev[j].w * pv.w;
        out[(size_t)m * DDIM + nn[j]] = acc[i][j][r] + b2v[j] + sc * lora;
      }
    }
  }
}

extern "C" void kernel_launch(void* const* d_in, const int* in_sizes, int n_in,
                              void* d_out, int out_size, void* d_ws, size_t ws_size,
                              hipStream_t stream) {
  const float* x     = (const float*)d_in[0];
  const float* W1    = (const float*)d_in[1];
  const float* b1    = (const float*)d_in[2];
  const float* W2    = (const float*)d_in[3];
  const float* b2    = (const float*)d_in[4];
  const float* scale = (const float*)d_in[5];
  float* out = (float*)d_out;

  char* ws = (char*)d_ws;
  unsigned short* xb   = (unsigned short*)(ws);                // 16 MiB
  unsigned short* w1b  = (unsigned short*)(ws + 16777216);     //  8 MiB
  unsigned short* w2b  = (unsigned short*)(ws + 25165824);     //  8 MiB
  unsigned short* hact = (unsigned short*)(ws + 33554432);     // 64 MiB
  float*          p1   = (float*)(ws + 100663296);             // 128 KiB

  pre_kernel<<<dim3(10240), dim3(256), 0, stream>>>(x, W1, W2, xb, w1b, w2b, p1);
  gemm1_kernel<<<dim3(2048), dim3(256), 0, stream>>>(xb, w1b, x, b1, p1, scale, hact);
  gemm2_kernel<<<dim3(512), dim3(256), 0, stream>>>(hact, w2b, x, b2, scale, out);
}